// Round 3
// baseline (10404.535 us; speedup 1.0000x reference)
//
#include <hip/hip_runtime.h>
#include <stdint.h>
#include <math.h>

// Bayesian STDP persistent-scan kernel, v7: 64 workgroups x 2 outputs.
// vs v6: (1) NG=64/NO=2 — doubles active CUs (32->64), halves per-CU GEMM1
// and post_pre work; psp stays fully replicated per WG (132 KB, 1 WG/CU).
// (2) Softmax stats are computed and posted per-wave from registers right
// after the GEMM1 butterfly — no uS round trip, no pre-post barrier.
// (3) Step order A(+post) -> bar -> [issue poll loads] -> F -> C -> bar ->
// D -> bar: the psp recurrence hides the cross-XCD stats propagation that
// v6 exposed; phase D consumes psp(t) from a rotation-swizzled register
// preload (conflict-free). 3 LDS-only barriers/step.

#define TSTEPS 1000
#define BB     64
#define NINF   512
#define NOUTT  128
#define NG     64
#define NO     2
#define NTHR   1024
#define PSPD   0.9f
#define VD     0.9f
#define LRC    1e-3f
#define PS     516                  // padded row stride (floats), 16B-multiple

__device__ __forceinline__ void sync_lds() {
  // barrier draining only LDS (lgkmcnt=0, vmcnt=63, expcnt=7)
  asm volatile("" ::: "memory");
  __builtin_amdgcn_s_waitcnt(0xC07F);
  __builtin_amdgcn_s_barrier();
  asm volatile("" ::: "memory");
}

__device__ __forceinline__ float2 aload_f2(const float* p) {
  unsigned long long u = __hip_atomic_load((const unsigned long long*)p,
      __ATOMIC_RELAXED, __HIP_MEMORY_SCOPE_AGENT);
  float2 r;
  r.x = __uint_as_float((unsigned)u);
  r.y = __uint_as_float((unsigned)(u >> 32));
  return r;
}
__device__ __forceinline__ void astore_f2(float* p, float x, float y) {
  unsigned long long u = (unsigned long long)__float_as_uint(x)
                       | ((unsigned long long)__float_as_uint(y) << 32);
  __hip_atomic_store((unsigned long long*)p, u, __ATOMIC_RELAXED, __HIP_MEMORY_SCOPE_AGENT);
}

__global__ __launch_bounds__(NTHR)
void bstdp_kernel(const float* __restrict__ spikes,   // [T][B][NIN]
                  const float* __restrict__ weight,   // [NOUT][NIN]
                  const float* __restrict__ bias,     // [NOUT]
                  float* __restrict__ out,            // [T][B][NOUT] ++ [B][NOUT]
                  float* __restrict__ ws)
{
  const int g   = blockIdx.x;
  const int tid = threadIdx.x;

  float* stats = ws;                       // [2][NG][BB][2] floats (tag in sign of ssum)

  __shared__ __align__(16) float psp[BB*PS];   // 132 KB replicated psp trace
  __shared__ __align__(16) float Wt[NO*PS];    // 4.1 KB W tile (padded rows)
  __shared__ __align__(16) float zT[BB*NO];    // z [b][o]
  __shared__ __align__(16) float uS[NO*BB];    // membrane [o][b]
  __shared__ float pmS[16];                    // per-wave pm partials [w][o]
  __shared__ float btS[NO];

  // ---- prologue: W tile, bias, u=0, psp(0) = spikes(0) ----
  Wt[(tid>>9)*PS + (tid&511)] = weight[g*(NO*NINF) + tid];   // 1024 elems, 1/thread
  if (tid < NO)    btS[tid] = bias[g*NO + tid];
  if (tid < NO*BB) uS[tid] = 0.0f;
  #pragma unroll
  for (int k = 0; k < 8; ++k) {
    int j = tid*4 + k*4096;
    *(float4*)&psp[(j>>9)*PS + (j&511)] = *(const float4*)(spikes + j);
  }
  __syncthreads();

  const int w  = tid >> 6;                    // wave 0..15 (owns batch rows w*4..w*4+3)
  const int ln = tid & 63;
  const int c0 = (ln & 31) * 4 + (ln >> 5) * 128;   // GEMM1 column base
  const int q8 = tid & 7,  b4 = tid >> 3;     // phase C (tid<512): 8 groups/thread
  const int dbh = tid & 3;                    // phase D: batch quarter
  const int di  = (tid >> 2) * 2;             // phase D: column pair

  for (int t = 0; t < TSTEPS; ++t) {
    const int sb = t & 1;
    const float sgn = ((t >> 1) & 1) ? -1.0f : 1.0f;   // epoch parity tag

    // ---------- A: spikes(t+1) prefetch + GEMM1 (wave-owns-4-rows) ----------
    float4 spn[8];
    if (t + 1 < TSTEPS) {
      const float* sp = spikes + (size_t)(t+1)*(BB*NINF) + tid*4;
      #pragma unroll
      for (int k = 0; k < 8; ++k) spn[k] = *(const float4*)(sp + k*4096);
    }
    {
      float acc[8];
      #pragma unroll
      for (int i = 0; i < 8; ++i) acc[i] = 0.0f;
      #pragma unroll
      for (int k = 0; k < 2; ++k) {
        const int cb = c0 + k*256;
        float4 p[4], wv[2];
        #pragma unroll
        for (int r = 0; r < 4; ++r) p[r]  = *(const float4*)&psp[(w*4+r)*PS + cb];
        #pragma unroll
        for (int o = 0; o < 2; ++o) wv[o] = *(const float4*)&Wt[o*PS + cb];
        #pragma unroll
        for (int r = 0; r < 4; ++r) {
          #pragma unroll
          for (int o = 0; o < 2; ++o) {
            acc[r*2+o] = fmaf(p[r].x, wv[o].x, fmaf(p[r].y, wv[o].y,
                         fmaf(p[r].z, wv[o].z, fmaf(p[r].w, wv[o].w, acc[r*2+o]))));
          }
        }
      }
      // value-folding butterfly: lane ln ends with full sum of acc[ln&7]
      #pragma unroll
      for (int j = 0; j < 4; ++j) {             // xor1: 8 -> 4
        float s_ = (ln & 1) ? acc[2*j]   : acc[2*j+1];
        float k_ = (ln & 1) ? acc[2*j+1] : acc[2*j];
        acc[j] = k_ + __shfl_xor(s_, 1);
      }
      #pragma unroll
      for (int j = 0; j < 2; ++j) {             // xor2: 4 -> 2
        float s_ = (ln & 2) ? acc[2*j]   : acc[2*j+1];
        float k_ = (ln & 2) ? acc[2*j+1] : acc[2*j];
        acc[j] = k_ + __shfl_xor(s_, 2);
      }
      {                                          // xor4: 2 -> 1
        float s_ = (ln & 4) ? acc[0] : acc[1];
        float k_ = (ln & 4) ? acc[1] : acc[0];
        acc[0] = k_ + __shfl_xor(s_, 4);
      }
      acc[0] += __shfl_xor(acc[0], 8);
      acc[0] += __shfl_xor(acc[0], 16);
      acc[0] += __shfl_xor(acc[0], 32);
      // lanes 0..7: idx = ln -> (r = ln>>1, o = ln&1); membrane + in-register stats post
      float unew = 0.0f;
      if (ln < 8) {
        const int o = ln & 1, r = ln >> 1;
        const int row = w*4 + r;
        unew = VD*uS[o*BB + row] + acc[0] + btS[o];
        uS[o*BB + row] = unew;
      }
      float uo = __shfl_xor(unew, 1);            // partner output's u for this row
      if (ln < 8 && !(ln & 1)) {
        const int row = w*4 + (ln >> 1);
        float mx = fmaxf(unew, uo);
        float ssum = expf(unew - mx) + expf(uo - mx);   // in [1,2]
        astore_f2(stats + ((size_t)(sb*NG + g)*BB + row)*2, mx, ssum*sgn);
      }
    }

    // ---------- Apre: preload phase-D psp slice (rotation => conflict-free) ----------
    float2 pv[16];
    if (t + 1 < TSTEPS) {
      #pragma unroll
      for (int i = 0; i < 16; ++i) {
        int b = dbh*16 + ((i + 2*dbh) & 15);    // bank shifts {0,8,16,24}
        pv[i] = *(const float2*)&psp[b*PS + di];
      }
    }
    sync_lds();   // (1) uS complete; all psp(t) reads complete

    // ---------- C-issue: fire poll loads before F so latency hides under it ----------
    float2 msv[8];
    if (tid < 512) {
      #pragma unroll
      for (int k = 0; k < 8; ++k)
        msv[k] = aload_f2(stats + ((size_t)(sb*NG + (q8*8 + k))*BB + b4)*2);
    }

    // ---------- F: psp recurrence — hides cross-XCD stats propagation ----------
    if (t + 1 < TSTEPS) {
      #pragma unroll
      for (int k = 0; k < 8; ++k) {
        int j = tid*4 + k*4096;
        float* pa = &psp[(j>>9)*PS + (j&511)];
        float4 p = *(float4*)pa;
        p.x = PSPD*p.x + spn[k].x;
        p.y = PSPD*p.y + spn[k].y;
        p.z = PSPD*p.z + spn[k].z;
        p.w = PSPD*p.w + spn[k].w;
        *(float4*)pa = p;
      }
    }

    // ---------- C: validate + merge stats, z, out store, pm partials ----------
    if (tid < 512) {
      for (;;) {
        int bad = 0;
        #pragma unroll
        for (int k = 0; k < 8; ++k)
          bad |= (msv[k].y * sgn >= 1.0f) ? 0 : (1 << k);   // valid iff tagged this epoch
        if (!bad) break;
        __builtin_amdgcn_s_sleep(1);
        #pragma unroll
        for (int k = 0; k < 8; ++k)
          if (bad & (1 << k))
            msv[k] = aload_f2(stats + ((size_t)(sb*NG + (q8*8 + k))*BB + b4)*2);
      }
      float M = -1e30f, S = 0.f;
      #pragma unroll
      for (int k = 0; k < 8; ++k) {
        float mxv = msv[k].x, sv = fabsf(msv[k].y);
        float Mn = fmaxf(M, mxv);
        S = S*expf(M - Mn) + sv*expf(mxv - Mn);
        M = Mn;
      }
      #pragma unroll
      for (int m = 1; m < 8; m <<= 1) {
        float Mo = __shfl_xor(M, m);
        float So = __shfl_xor(S, m);
        float Mn = fmaxf(M, Mo);
        S = S*expf(M - Mn) + So*expf(Mo - Mn);
        M = Mn;
      }
      float v = 0.0f;
      if (q8 < NO) {
        float z = expf(uS[q8*BB + b4] - M) / S;
        zT[b4*NO + q8] = z;
        __builtin_nontemporal_store(z,
            out + (size_t)t*(BB*NOUTT) + (size_t)b4*NOUTT + g*NO + q8);
        v = z;
      }
      #pragma unroll
      for (int m = 8; m < 64; m <<= 1) v += __shfl_xor(v, m);   // sum over wave's 8 b's
      if ((tid & 63) < NO) pmS[(tid >> 6)*NO + q8] = v;
    }
    sync_lds();   // (2) zT, pmS visible

    // ---------- D/E: post_pre from registers + W,b update ----------
    if (t + 1 < TSTEPS) {
      float pp[NO][2] = {};
      #pragma unroll
      for (int i = 0; i < 16; ++i) {
        int b = dbh*16 + ((i + 2*dbh) & 15);
        float2 pvl = pv[i];
        float2 z2 = *(const float2*)&zT[b*NO];
        pp[0][0] = fmaf(z2.x, pvl.x, pp[0][0]); pp[0][1] = fmaf(z2.x, pvl.y, pp[0][1]);
        pp[1][0] = fmaf(z2.y, pvl.x, pp[1][0]); pp[1][1] = fmaf(z2.y, pvl.y, pp[1][1]);
      }
      // combine the 4 batch-quarters (lanes differing in tid&3)
      #pragma unroll
      for (int m = 1; m < 4; m <<= 1) {
        #pragma unroll
        for (int o = 0; o < NO; ++o) {
          pp[o][0] += __shfl_xor(pp[o][0], m);
          pp[o][1] += __shfl_xor(pp[o][1], m);
        }
      }
      if (dbh < NO) {                            // lane dbh==o updates W[o][di..di+1]
        float ppx = (dbh == 0) ? pp[0][0] : pp[1][0];
        float ppy = (dbh == 0) ? pp[0][1] : pp[1][1];
        float pm = 0.0f;
        #pragma unroll
        for (int k = 0; k < 8; ++k) pm += pmS[k*NO + dbh];
        pm *= (1.0f/BB);
        float* wp = &Wt[dbh*PS + di];
        float w0 = wp[0], w1 = wp[1];
        wp[0] = w0 + LRC*(expf(-w0)*ppx*(1.0f/BB) - pm);
        wp[1] = w1 + LRC*(expf(-w1)*ppy*(1.0f/BB) - pm);
      }
      if (tid < NO) {
        float pmb = 0.0f;
        #pragma unroll
        for (int k = 0; k < 8; ++k) pmb += pmS[k*NO + tid];
        pmb *= (1.0f/BB);
        float bv = btS[tid];
        btS[tid] = bv + LRC*(expf(-bv) - 1.0f)*pmb;
      }
    }
    sync_lds();   // (3) Wt/btS + psp(t+1) visible for next A; zT free
  }

  // ---- epilogue: u_final ----
  if (tid < BB*NO) {
    const int o = tid & 1, b = tid >> 1;
    __builtin_nontemporal_store(uS[o*BB + b],
        out + (size_t)TSTEPS*(BB*NOUTT) + (size_t)b*NOUTT + g*NO + o);
  }
}

extern "C" void kernel_launch(void* const* d_in, const int* in_sizes, int n_in,
                              void* d_out, int out_size, void* d_ws, size_t ws_size,
                              hipStream_t stream) {
  const float* spikes = (const float*)d_in[0];   // [1000,64,512] fp32
  const float* weight = (const float*)d_in[1];   // [128,512] fp32
  const float* bias   = (const float*)d_in[2];   // [128] fp32
  float* out = (float*)d_out;                    // [1000*64*128] ++ [64*128]
  float* ws  = (float*)d_ws;

  bstdp_kernel<<<dim3(NG), dim3(NTHR), 0, stream>>>(spikes, weight, bias, out, ws);
}

// Round 4
// 7042.358 us; speedup vs baseline: 1.4774x; 1.4774x over previous
//
#include <hip/hip_runtime.h>
#include <stdint.h>
#include <math.h>

// Bayesian STDP persistent-scan kernel, v8: register-resident psp.
// vs v7: psp lives in VGPRs, partitioned to match GEMM1 exactly — thread
// (wave w, lane ln) owns rows 4w..4w+3 x cols {c0..c0+3, c0+256..c0+259}.
// GEMM1 reads no psp from LDS; the psp recurrence (F) is 32 register FMAs;
// softmax merge is fully in-wave (wave w handles its own 4 rows; u in lane
// registers), killing the uS round trip and two barriers. post_pre reduces
// wave-partials via one conflict-free LDS scratch stage; W is updated in
// LDS by 256 threads. 2 LDS barriers/step. Exchange: tag-validated relaxed
// atomics (sign of ssum = epoch parity), unchanged invariants.

#define TSTEPS 1000
#define BB     64
#define NINF   512
#define NOUTT  128
#define NG     64
#define NO     2
#define NTHR   1024
#define PSPD   0.9f
#define VD     0.9f
#define LRC    1e-3f
#define WLS    520                 // W row stride (floats)
#define SCS    1028                // scratch row stride (floats), 16B-aligned

__device__ __forceinline__ void sync_lds() {
  // barrier draining only LDS (lgkmcnt=0, vmcnt=63, expcnt=7)
  asm volatile("" ::: "memory");
  __builtin_amdgcn_s_waitcnt(0xC07F);
  __builtin_amdgcn_s_barrier();
  asm volatile("" ::: "memory");
}
__device__ __forceinline__ void wait_lds() {
  // in-wave LDS write->read visibility (no barrier)
  asm volatile("" ::: "memory");
  __builtin_amdgcn_s_waitcnt(0xC07F);
  asm volatile("" ::: "memory");
}

__device__ __forceinline__ float2 aload_f2(const float* p) {
  unsigned long long u = __hip_atomic_load((const unsigned long long*)p,
      __ATOMIC_RELAXED, __HIP_MEMORY_SCOPE_AGENT);
  float2 r;
  r.x = __uint_as_float((unsigned)u);
  r.y = __uint_as_float((unsigned)(u >> 32));
  return r;
}
__device__ __forceinline__ void astore_f2(float* p, float x, float y) {
  unsigned long long u = (unsigned long long)__float_as_uint(x)
                       | ((unsigned long long)__float_as_uint(y) << 32);
  __hip_atomic_store((unsigned long long*)p, u, __ATOMIC_RELAXED, __HIP_MEMORY_SCOPE_AGENT);
}

__global__ __launch_bounds__(NTHR)
void bstdp_kernel(const float* __restrict__ spikes,   // [T][B][NIN]
                  const float* __restrict__ weight,   // [NOUT][NIN]
                  const float* __restrict__ bias,     // [NOUT]
                  float* __restrict__ out,            // [T][B][NOUT] ++ [B][NOUT]
                  float* __restrict__ ws)
{
  const int g   = blockIdx.x;
  const int tid = threadIdx.x;

  float* stats = ws;                       // [2][NG][BB][2] floats (tag in sign of ssum)

  __shared__ __align__(16) float scratch[16*SCS];  // 65.8 KB per-wave pp partials
  __shared__ __align__(16) float Wl[NO*WLS];       // 4.2 KB W (padded rows)
  __shared__ __align__(16) float zW[16*8];         // per-wave z broadcast
  __shared__ float pmA[2][2];                      // double-buffered post_mean acc

  const int w    = tid >> 6;               // wave 0..15, owns rows 4w..4w+3
  const int ln   = tid & 63;
  const int c0   = (ln & 31)*4 + (ln >> 5)*128;   // column block base
  const int row0 = w*4;

  // ---- prologue ----
  Wl[(tid >> 9)*WLS + (tid & 511)] = weight[g*(NO*NINF) + tid];
  if (tid < 4) ((float*)pmA)[tid] = 0.0f;
  float bt0 = bias[g*NO + 0];
  float bt1 = bias[g*NO + 1];
  float u = 0.0f;                          // membrane for (row0+(ln>>1), ln&1), lanes 0..7
  float4 P[4][2];                          // psp rows x 2 col-blocks (registers)
  #pragma unroll
  for (int r = 0; r < 4; ++r)
    #pragma unroll
    for (int k = 0; k < 2; ++k)
      P[r][k] = *(const float4*)(spikes + (size_t)(row0 + r)*NINF + c0 + k*256);
  __syncthreads();

  const int sub = ln & 15;                 // C-phase: 16 lanes per row

  for (int t = 0; t < TSTEPS; ++t) {
    const int   sb  = t & 1;
    const float sgn = ((t >> 1) & 1) ? -1.0f : 1.0f;   // epoch parity tag

    // ---------- spikes(t+1) prefetch (registers, ownership-aligned) ----------
    float4 spn[4][2];
    if (t + 1 < TSTEPS) {
      const float* sp = spikes + (size_t)(t + 1)*(BB*NINF);
      #pragma unroll
      for (int r = 0; r < 4; ++r)
        #pragma unroll
        for (int k = 0; k < 2; ++k)
          spn[r][k] = *(const float4*)(sp + (size_t)(row0 + r)*NINF + c0 + k*256);
    }

    // ---------- A: GEMM1 from registers (W from LDS) ----------
    {
      float4 wv[2][2];
      #pragma unroll
      for (int o = 0; o < 2; ++o)
        #pragma unroll
        for (int k = 0; k < 2; ++k)
          wv[o][k] = *(const float4*)&Wl[o*WLS + c0 + k*256];
      float acc[8];
      #pragma unroll
      for (int r = 0; r < 4; ++r)
        #pragma unroll
        for (int o = 0; o < 2; ++o) {
          float s0 = fmaf(P[r][0].x, wv[o][0].x, fmaf(P[r][0].y, wv[o][0].y,
                     fmaf(P[r][0].z, wv[o][0].z, P[r][0].w * wv[o][0].w)));
          acc[r*2+o] = fmaf(P[r][1].x, wv[o][1].x, fmaf(P[r][1].y, wv[o][1].y,
                       fmaf(P[r][1].z, wv[o][1].z, fmaf(P[r][1].w, wv[o][1].w, s0))));
        }
      // value-folding butterfly: lane ln ends with full sum of acc[ln&7]
      #pragma unroll
      for (int j = 0; j < 4; ++j) {             // xor1: 8 -> 4
        float s_ = (ln & 1) ? acc[2*j]   : acc[2*j+1];
        float k_ = (ln & 1) ? acc[2*j+1] : acc[2*j];
        acc[j] = k_ + __shfl_xor(s_, 1);
      }
      #pragma unroll
      for (int j = 0; j < 2; ++j) {             // xor2: 4 -> 2
        float s_ = (ln & 2) ? acc[2*j]   : acc[2*j+1];
        float k_ = (ln & 2) ? acc[2*j+1] : acc[2*j];
        acc[j] = k_ + __shfl_xor(s_, 2);
      }
      {                                          // xor4: 2 -> 1
        float s_ = (ln & 4) ? acc[0] : acc[1];
        float k_ = (ln & 4) ? acc[1] : acc[0];
        acc[0] = k_ + __shfl_xor(s_, 4);
      }
      acc[0] += __shfl_xor(acc[0], 8);
      acc[0] += __shfl_xor(acc[0], 16);
      acc[0] += __shfl_xor(acc[0], 32);
      // lanes 0..7 hold (r = ln>>1, o = ln&1): membrane update + tagged post
      float unew = 0.0f;
      if (ln < 8) {
        unew = VD*u + acc[0] + ((ln & 1) ? bt1 : bt0);
        u = unew;
      }
      float uo = __shfl_xor(unew, 1);
      if (ln < 8 && !(ln & 1)) {
        const int prow = row0 + (ln >> 1);
        float mx = fmaxf(unew, uo);
        float ss = expf(unew - mx) + expf(uo - mx);   // in [1,2]
        astore_f2(stats + ((size_t)(sb*NG + g)*BB + prow)*2, mx, ss*sgn);
      }
    }

    // ---------- C: in-wave poll + merge for this wave's 4 rows ----------
    float z = 0.0f;
    {
      const int crow = row0 + (ln >> 4);          // 16 lanes per row
      float* sbase = stats + (size_t)sb*NG*BB*2;
      float2 msv[4];
      #pragma unroll
      for (int k = 0; k < 4; ++k)
        msv[k] = aload_f2(sbase + ((size_t)(sub*4 + k)*BB + crow)*2);
      for (;;) {
        int bad = 0;
        #pragma unroll
        for (int k = 0; k < 4; ++k)
          bad |= (msv[k].y * sgn >= 1.0f) ? 0 : (1 << k);
        if (!bad) break;
        __builtin_amdgcn_s_sleep(1);
        #pragma unroll
        for (int k = 0; k < 4; ++k)
          if (bad & (1 << k))
            msv[k] = aload_f2(sbase + ((size_t)(sub*4 + k)*BB + crow)*2);
      }
      float M = -1e30f, S = 0.0f;
      #pragma unroll
      for (int k = 0; k < 4; ++k) {
        float mxv = msv[k].x, sv = fabsf(msv[k].y);
        float Mn = fmaxf(M, mxv);
        S = S*expf(M - Mn) + sv*expf(mxv - Mn);
        M = Mn;
      }
      #pragma unroll
      for (int m = 1; m < 16; m <<= 1) {          // merge across the 16-lane group
        float Mo = __shfl_xor(M, m);
        float So = __shfl_xor(S, m);
        float Mn = fmaxf(M, Mo);
        S = S*expf(M - Mn) + So*expf(Mo - Mn);
        M = Mn;
      }
      // route row stats to lanes 0..7 (lane 2r/2r+1 <- group r's lane r*16)
      int src = (ln >> 1) << 4;
      float Mb = __shfl(M, src);
      float Sb = __shfl(S, src);
      if (ln < 8) {
        z = expf(u - Mb) / Sb;
        __builtin_nontemporal_store(z,
            out + (size_t)t*(BB*NOUTT) + (size_t)(row0 + (ln >> 1))*NOUTT + g*NO + (ln & 1));
      }
      float v = z;                                // post_mean partial (4 rows of this wave)
      v += __shfl_xor(v, 2);
      v += __shfl_xor(v, 4);
      if (ln < 2) atomicAdd(&pmA[sb][ln], v);
      // z broadcast to the whole wave (in-wave LDS round trip, no barrier)
      if (ln < 8) zW[w*8 + ln] = z;
    }
    wait_lds();
    {
      float4 zq0 = *(const float4*)&zW[w*8];      // z(0,0) z(0,1) z(1,0) z(1,1)
      float4 zq1 = *(const float4*)&zW[w*8 + 4];  // z(2,0) z(2,1) z(3,0) z(3,1)

      // ---------- D1: post_pre wave-partials -> scratch; F: psp advance ----------
      if (t + 1 < TSTEPS) {
        #pragma unroll
        for (int o = 0; o < 2; ++o) {
          float z0 = o ? zq0.y : zq0.x;
          float z1 = o ? zq0.w : zq0.z;
          float z2 = o ? zq1.y : zq1.x;
          float z3 = o ? zq1.w : zq1.z;
          #pragma unroll
          for (int k = 0; k < 2; ++k) {
            float4 r;
            r.x = fmaf(z0, P[0][k].x, fmaf(z1, P[1][k].x, fmaf(z2, P[2][k].x, z3*P[3][k].x)));
            r.y = fmaf(z0, P[0][k].y, fmaf(z1, P[1][k].y, fmaf(z2, P[2][k].y, z3*P[3][k].y)));
            r.z = fmaf(z0, P[0][k].z, fmaf(z1, P[1][k].z, fmaf(z2, P[2][k].z, z3*P[3][k].z)));
            r.w = fmaf(z0, P[0][k].w, fmaf(z1, P[1][k].w, fmaf(z2, P[2][k].w, z3*P[3][k].w)));
            *(float4*)&scratch[w*SCS + o*512 + c0 + k*256] = r;
          }
        }
        #pragma unroll
        for (int r = 0; r < 4; ++r)
          #pragma unroll
          for (int k = 0; k < 2; ++k) {
            P[r][k].x = fmaf(PSPD, P[r][k].x, spn[r][k].x);
            P[r][k].y = fmaf(PSPD, P[r][k].y, spn[r][k].y);
            P[r][k].z = fmaf(PSPD, P[r][k].z, spn[r][k].z);
            P[r][k].w = fmaf(PSPD, P[r][k].w, spn[r][k].w);
          }
      }
    }
    sync_lds();   // (1) scratch + pmA complete

    // ---------- D2: reduce partials, W update (LDS), bias (registers) ----------
    if (t + 1 < TSTEPS) {
      if (tid < 256) {
        const int o2  = tid >> 7;
        const int cc4 = (tid & 127)*4;
        float4 s; s.x = 0.0f; s.y = 0.0f; s.z = 0.0f; s.w = 0.0f;
        #pragma unroll
        for (int k = 0; k < 16; ++k) {
          float4 p = *(const float4*)&scratch[k*SCS + o2*512 + cc4];
          s.x += p.x; s.y += p.y; s.z += p.z; s.w += p.w;
        }
        float pmv = pmA[sb][o2] * (1.0f/BB);
        float4 wl = *(float4*)&Wl[o2*WLS + cc4];
        wl.x += LRC*(expf(-wl.x)*s.x*(1.0f/BB) - pmv);
        wl.y += LRC*(expf(-wl.y)*s.y*(1.0f/BB) - pmv);
        wl.z += LRC*(expf(-wl.z)*s.z*(1.0f/BB) - pmv);
        wl.w += LRC*(expf(-wl.w)*s.w*(1.0f/BB) - pmv);
        *(float4*)&Wl[o2*WLS + cc4] = wl;
      }
      float pm0 = pmA[sb][0]*(1.0f/BB);
      float pm1 = pmA[sb][1]*(1.0f/BB);
      bt0 += LRC*(expf(-bt0) - 1.0f)*pm0;         // redundant per-thread (consistent)
      bt1 += LRC*(expf(-bt1) - 1.0f)*pm1;
      if (tid == 0) { pmA[sb ^ 1][0] = 0.0f; pmA[sb ^ 1][1] = 0.0f; }
    }
    sync_lds();   // (2) Wl updated, pmA slot cleared for t+1
  }

  // ---- epilogue: u_final ----
  if (ln < 8) {
    __builtin_nontemporal_store(u,
        out + (size_t)TSTEPS*(BB*NOUTT) + (size_t)(row0 + (ln >> 1))*NOUTT + g*NO + (ln & 1));
  }
}

extern "C" void kernel_launch(void* const* d_in, const int* in_sizes, int n_in,
                              void* d_out, int out_size, void* d_ws, size_t ws_size,
                              hipStream_t stream) {
  const float* spikes = (const float*)d_in[0];   // [1000,64,512] fp32
  const float* weight = (const float*)d_in[1];   // [128,512] fp32
  const float* bias   = (const float*)d_in[2];   // [128] fp32
  float* out = (float*)d_out;                    // [1000*64*128] ++ [64*128]
  float* ws  = (float*)d_ws;

  bstdp_kernel<<<dim3(NG), dim3(NTHR), 0, stream>>>(spikes, weight, bias, out, ws);
}